// Round 1
// baseline (4587.761 us; speedup 1.0000x reference)
//
#include <hip/hip_runtime.h>
#include <math.h>

#define N_NODES 40000
#define N_EDGES 640000
#define D 64
#define HEADS 4
#define K2V 64
#define ET 16
#define NT0 16

__device__ __forceinline__ float softplus_f(float x) {
    return x > 20.f ? x : log1pf(__expf(x));
}
__device__ __forceinline__ float sigmoid_f(float x) {
    return 1.f / (1.f + __expf(-x));
}

// ---------- K_T: build transposed weight copies for contiguous k-access ----------
__global__ void k_transpose(const float* __restrict__ Wa, const float* __restrict__ W2g,
                            const float* __restrict__ W2, float* __restrict__ WaT2,
                            float* __restrict__ W2gT, float* __restrict__ W2T) {
    int idx = blockIdx.x * blockDim.x + threadIdx.x;
    int stride = gridDim.x * blockDim.x;
    // WaT2[c*64+k] = Wa[(64+k)*256 + c]   (c<256, k<64)
    for (int i = idx; i < 256 * 64; i += stride) {
        int c = i >> 6, k = i & 63;
        WaT2[i] = Wa[(64 + k) * 256 + c];
    }
    // W2gT[c*64+k] = W2g[k*64+c], W2T likewise (c<64, k<64)
    for (int i = idx; i < 64 * 64; i += stride) {
        int c = i >> 6, k = i & 63;
        W2gT[i] = W2g[k * 64 + c];
        W2T[i]  = W2[k * 64 + c];
    }
}

// ---------- K0: node precompute  nodeA[n, 0:640] ----------
// layout per node: [Ag1(64) Ag2(64) Ag3(64) Am1(64) Am2(64) Am3(64) Axa(256)]
__global__ __launch_bounds__(256) void k_node_pre(const float* __restrict__ X,
                                                  const float* __restrict__ Wg,
                                                  const float* __restrict__ Wm,
                                                  const float* __restrict__ Wa,
                                                  float* __restrict__ nodeA) {
    __shared__ float xs[NT0 * 64];
    int t = threadIdx.x;
    int n0 = blockIdx.x * NT0;
    ((float4*)xs)[t] = ((const float4*)(X + (size_t)n0 * 64))[t];
    __syncthreads();
    for (int c = t; c < 640; c += 256) {
        const float* wptr;
        int ld;
        if (c < 192)      { wptr = Wg + (c >> 6) * 64 * 64 + (c & 63); ld = 64; }
        else if (c < 384) { wptr = Wm + ((c - 192) >> 6) * 64 * 64 + (c & 63); ld = 64; }
        else              { wptr = Wa + (c - 384); ld = 256; }
        float acc[NT0];
#pragma unroll
        for (int n = 0; n < NT0; n++) acc[n] = 0.f;
        for (int kc = 0; kc < 16; kc++) {
            float w0 = wptr[(4 * kc + 0) * ld];
            float w1 = wptr[(4 * kc + 1) * ld];
            float w2 = wptr[(4 * kc + 2) * ld];
            float w3 = wptr[(4 * kc + 3) * ld];
#pragma unroll
            for (int n = 0; n < NT0; n++) {
                float4 x = ((float4*)xs)[n * 16 + kc];
                acc[n] += x.x * w0 + x.y * w1 + x.z * w2 + x.w * w3;
            }
        }
#pragma unroll
        for (int n = 0; n < NT0; n++) nodeA[(size_t)(n0 + n) * 640 + c] = acc[n];
    }
}

// ---------- K1: alpha_raw (post-bn softplus) + segment max ----------
__global__ __launch_bounds__(256) void k_alpha(
    const float* __restrict__ ea, const int* __restrict__ src, const int* __restrict__ tgt,
    const float* __restrict__ nodeA, const float* __restrict__ WaT2,
    const float* __restrict__ att, const float* __restrict__ gamma,
    const float* __restrict__ beta,
    float* __restrict__ alphaBuf, unsigned int* __restrict__ segMax) {
    __shared__ float eaS[ET * 64];
    __shared__ int srcS[ET], tgtS[ET];
    int t = threadIdx.x;
    size_t e0 = (size_t)blockIdx.x * ET;
    if (t < ET) { srcS[t] = src[e0 + t]; tgtS[t] = tgt[e0 + t]; }
    ((float4*)eaS)[t] = ((const float4*)(ea + e0 * 64))[t];
    __syncthreads();
    int c = t;
    int h = c >> 6, d = c & 63;
    float4 w[16];
    const float4* wp = (const float4*)(WaT2 + c * 64);
#pragma unroll
    for (int i = 0; i < 16; i++) w[i] = wp[i];
    float atti = att[h * 128 + d];
    float attj = att[h * 128 + 64 + d];
    float inv_s = 1.f / sqrtf(1.f + 1e-5f);
    float g = gamma[h], b = beta[h];
    for (int e = 0; e < ET; e++) {
        const float4* eap = (const float4*)(eaS + e * 64);
        float acc = 0.f;
#pragma unroll
        for (int i = 0; i < 16; i++) {
            float4 a = eap[i];
            acc += a.x * w[i].x + a.y * w[i].y + a.z * w[i].z + a.w * w[i].w;
        }
        int s = srcS[e], tg = tgtS[e];
        float oi = softplus_f(nodeA[(size_t)s * 640 + 384 + c] + acc);
        float oj = softplus_f(nodeA[(size_t)tg * 640 + 384 + c] + acc);
        float part = oi * atti + oj * attj;
#pragma unroll
        for (int o = 32; o > 0; o >>= 1) part += __shfl_xor(part, o, 64);
        if ((t & 63) == 0) {
            float araw = softplus_f(part);
            float av = softplus_f(araw * inv_s * g + b);
            alphaBuf[(e0 + e) * 4 + h] = av;
            atomicMax(&segMax[s * 4 + h], __float_as_uint(av));
        }
    }
}

// ---------- K2: exp(alpha - max) + segment sum ----------
__global__ __launch_bounds__(256) void k_exp(const int* __restrict__ src,
                                             float* __restrict__ alphaBuf,
                                             const unsigned int* __restrict__ segMax,
                                             float* __restrict__ segSum) {
    int i = blockIdx.x * blockDim.x + threadIdx.x;
    if (i >= N_EDGES * HEADS) return;
    int e = i >> 2, h = i & 3;
    int s = src[e];
    float m = __uint_as_float(segMax[s * 4 + h]);
    float a = __expf(alphaBuf[i] - m);
    alphaBuf[i] = a;
    atomicAdd(&segSum[s * 4 + h], a);
}

// ---------- K3: out_j, z1, pw branch, gates, combine, scatter ----------
__global__ __launch_bounds__(256) void k_final(
    const float* __restrict__ ea, const float* __restrict__ pw,
    const float* __restrict__ rij,
    const int* __restrict__ src, const int* __restrict__ tgt,
    const float* __restrict__ nodeA, const float* __restrict__ WaT2,
    const float* __restrict__ W2gT, const float* __restrict__ W2T,
    const float* __restrict__ alphaBuf, const float* __restrict__ segSum,
    float* __restrict__ out) {
    __shared__ float bufA[ET * 64];   // ea, then pw
    __shared__ float bufB[ET * 64];   // pw*gate
    __shared__ float q[ET * 256];     // out_j * alpha/4
    __shared__ int srcS[ET], tgtS[ET];
    __shared__ float rS[ET];
    int t = threadIdx.x;
    size_t e0 = (size_t)blockIdx.x * ET;
    if (t < ET) {
        srcS[t] = src[e0 + t];
        tgtS[t] = tgt[e0 + t];
        float r = rij[e0 + t];
        if (r == 0.f) r = 1e-8f;
        rS[t] = 1.f / r;
    }
    ((float4*)bufA)[t] = ((const float4*)(ea + e0 * 64))[t];
    __syncthreads();
    int c = t, h = c >> 6;
    {
        float4 w[16];
        const float4* wp = (const float4*)(WaT2 + c * 64);
#pragma unroll
        for (int i = 0; i < 16; i++) w[i] = wp[i];
        for (int e = 0; e < ET; e++) {
            const float4* eap = (const float4*)(bufA + e * 64);
            float acc = 0.f;
#pragma unroll
            for (int i = 0; i < 16; i++) {
                float4 a = eap[i];
                acc += a.x * w[i].x + a.y * w[i].y + a.z * w[i].z + a.w * w[i].w;
            }
            int tg = tgtS[e], s = srcS[e];
            float oj = softplus_f(nodeA[(size_t)tg * 640 + 384 + c] + acc);
            float aval = alphaBuf[(e0 + e) * 4 + h];
            float den = segSum[s * 4 + h] + 1e-16f;
            q[e * 256 + c] = oj * (aval / den) * 0.25f;
        }
    }
    __syncthreads();
    ((float4*)bufA)[t] = ((const float4*)(pw + e0 * 64))[t];
    __syncthreads();
    int eg = t >> 6;     // 0..3
    int cc = t & 63;     // feature dim
    {
        float4 wg[16];
        const float4* wp = (const float4*)(W2gT + cc * 64);
#pragma unroll
        for (int i = 0; i < 16; i++) wg[i] = wp[i];
#pragma unroll
        for (int ii = 0; ii < 4; ii++) {
            int e = eg + ii * 4;
            const float4* pwp = (const float4*)(bufA + e * 64);
            float acc = 0.f;
#pragma unroll
            for (int i = 0; i < 16; i++) {
                float4 a = pwp[i];
                acc += a.x * wg[i].x + a.y * wg[i].y + a.z * wg[i].z + a.w * wg[i].w;
            }
            float gate = sigmoid_f(acc);
            bufB[e * 64 + cc] = bufA[e * 64 + cc] * gate;
        }
    }
    __syncthreads();
    {
        float4 w2[16];
        const float4* wp = (const float4*)(W2T + cc * 64);
#pragma unroll
        for (int i = 0; i < 16; i++) w2[i] = wp[i];
#pragma unroll
        for (int ii = 0; ii < 4; ii++) {
            int e = eg + ii * 4;
            const float4* pgp = (const float4*)(bufB + e * 64);
            float z2 = 0.f;
#pragma unroll
            for (int i = 0; i < 16; i++) {
                float4 a = pgp[i];
                z2 += a.x * w2[i].x + a.y * w2[i].y + a.z * w2[i].z + a.w * w2[i].w;
            }
            float z1 = q[e * 256 + cc] + q[e * 256 + 64 + cc] +
                       q[e * 256 + 128 + cc] + q[e * 256 + 192 + cc];
            int s = srcS[e], tg = tgtS[e];
            float ir = rS[e];
            const float* As = nodeA + (size_t)s * 640;
            const float* At = nodeA + (size_t)tg * 640;
            float gl = As[cc] + At[64 + cc] + (As[128 + cc] - At[128 + cc]) * ir;
            float ml = As[192 + cc] + At[256 + cc] + (As[320 + cc] - At[320 + cc]) * ir;
            float egate = sigmoid_f(gl);
            float emlp = ml > 0.f ? ml : (__expf(ml) - 1.f);
            float z = egate * emlp * (z1 + z2);
            atomicAdd(&out[(size_t)s * 64 + cc], z);
        }
    }
}

extern "C" void kernel_launch(void* const* d_in, const int* in_sizes, int n_in,
                              void* d_out, int out_size, void* d_ws, size_t ws_size,
                              hipStream_t stream) {
    const float* input = (const float*)d_in[0];
    const float* rij   = (const float*)d_in[1];
    const float* pw    = (const float*)d_in[2];
    const float* ea    = (const float*)d_in[3];
    const float* Wg    = (const float*)d_in[4];
    const float* Wm    = (const float*)d_in[5];
    const float* W2    = (const float*)d_in[6];
    const float* W2g   = (const float*)d_in[7];
    const float* Wa    = (const float*)d_in[8];
    const float* att   = (const float*)d_in[9];
    const float* gamma = (const float*)d_in[10];
    const float* beta  = (const float*)d_in[11];
    const int* srcIdx  = (const int*)d_in[12];
    const int* tgtIdx  = (const int*)d_in[13];
    float* out = (float*)d_out;

    // workspace layout (bytes)
    char* wsb = (char*)d_ws;
    float* nodeA    = (float*)(wsb);                      // 40000*640*4 = 102,400,000
    float* alphaBuf = (float*)(wsb + 102400000);          // 640000*4*4  = 10,240,000
    unsigned int* segMax = (unsigned int*)(wsb + 112640000); // 40000*4*4 = 640,000
    float* segSum   = (float*)(wsb + 113280000);          // 640,000
    float* WaT2     = (float*)(wsb + 113920000);          // 65,536
    float* W2gT     = (float*)(wsb + 113985536);          // 16,384
    float* W2T      = (float*)(wsb + 114001920);          // 16,384

    // zero the atomic accumulators (segMax || segSum contiguous)
    hipMemsetAsync(wsb + 112640000, 0, 1280000, stream);
    // out = input  (scatter-add target)
    hipMemcpyAsync(d_out, (const void*)input, (size_t)N_NODES * 64 * sizeof(float),
                   hipMemcpyDeviceToDevice, stream);

    k_transpose<<<32, 256, 0, stream>>>(Wa, W2g, W2, WaT2, W2gT, W2T);
    k_node_pre<<<N_NODES / NT0, 256, 0, stream>>>(input, Wg, Wm, Wa, nodeA);
    k_alpha<<<N_EDGES / ET, 256, 0, stream>>>(ea, srcIdx, tgtIdx, nodeA, WaT2,
                                              att, gamma, beta, alphaBuf, segMax);
    k_exp<<<(N_EDGES * HEADS + 255) / 256, 256, 0, stream>>>(srcIdx, alphaBuf, segMax, segSum);
    k_final<<<N_EDGES / ET, 256, 0, stream>>>(ea, pw, rij, srcIdx, tgtIdx, nodeA,
                                              WaT2, W2gT, W2T, alphaBuf, segSum, out);
}

// Round 2
// 3097.490 us; speedup vs baseline: 1.4811x; 1.4811x over previous
//
#include <hip/hip_runtime.h>
#include <math.h>

#define N_NODES 40000
#define N_EDGES 640000
#define D 64
#define HEADS 4
#define NT0 16

typedef short short8 __attribute__((ext_vector_type(8)));
typedef float fragC __attribute__((ext_vector_type(4)));

__device__ __forceinline__ float softplus_f(float x) {
    return x > 20.f ? x : log1pf(__expf(x));
}
__device__ __forceinline__ float sigmoid_f(float x) {
    return 1.f / (1.f + __expf(-x));
}
__device__ __forceinline__ short f2bf(float f) {
    unsigned u = __float_as_uint(f);
    u += 0x7FFF + ((u >> 16) & 1);   // round-to-nearest-even
    return (short)(u >> 16);
}

// ---------- bf16 weight prep ----------
// WaTb[c*64+k] = bf16(Wa[(64+k)*256 + c])   c<256 (cols of Wa edge-attr half), k<64
// W2gTb[c*64+k] = bf16(W2g[k*64+c]), W2Tb likewise
__global__ void k_weights(const float* __restrict__ Wa, const float* __restrict__ W2g,
                          const float* __restrict__ W2, short* __restrict__ WaTb,
                          short* __restrict__ W2gTb, short* __restrict__ W2Tb) {
    int idx = blockIdx.x * blockDim.x + threadIdx.x;
    int stride = gridDim.x * blockDim.x;
    for (int i = idx; i < 256 * 64; i += stride) {
        int c = i >> 6, k = i & 63;
        WaTb[i] = f2bf(Wa[(64 + k) * 256 + c]);
    }
    for (int i = idx; i < 64 * 64; i += stride) {
        int c = i >> 6, k = i & 63;
        W2gTb[i] = f2bf(W2g[k * 64 + c]);
        W2Tb[i]  = f2bf(W2[k * 64 + c]);
    }
}

// ---------- K0: node precompute  nodeA[n, 0:640] ----------
// layout per node: [Ag1(64) Ag2(64) Ag3(64) Am1(64) Am2(64) Am3(64) Axa(256)]
__global__ __launch_bounds__(256) void k_node_pre(const float* __restrict__ X,
                                                  const float* __restrict__ Wg,
                                                  const float* __restrict__ Wm,
                                                  const float* __restrict__ Wa,
                                                  float* __restrict__ nodeA) {
    __shared__ float xs[NT0 * 64];
    int t = threadIdx.x;
    int n0 = blockIdx.x * NT0;
    ((float4*)xs)[t] = ((const float4*)(X + (size_t)n0 * 64))[t];
    __syncthreads();
    for (int c = t; c < 640; c += 256) {
        const float* wptr;
        int ld;
        if (c < 192)      { wptr = Wg + (c >> 6) * 64 * 64 + (c & 63); ld = 64; }
        else if (c < 384) { wptr = Wm + ((c - 192) >> 6) * 64 * 64 + (c & 63); ld = 64; }
        else              { wptr = Wa + (c - 384); ld = 256; }
        float acc[NT0];
#pragma unroll
        for (int n = 0; n < NT0; n++) acc[n] = 0.f;
        for (int kc = 0; kc < 16; kc++) {
            float w0 = wptr[(4 * kc + 0) * ld];
            float w1 = wptr[(4 * kc + 1) * ld];
            float w2 = wptr[(4 * kc + 2) * ld];
            float w3 = wptr[(4 * kc + 3) * ld];
#pragma unroll
            for (int n = 0; n < NT0; n++) {
                float4 x = ((float4*)xs)[n * 16 + kc];
                acc[n] += x.x * w0 + x.y * w1 + x.z * w2 + x.w * w3;
            }
        }
#pragma unroll
        for (int n = 0; n < NT0; n++) nodeA[(size_t)(n0 + n) * 640 + c] = acc[n];
    }
}

// ---------- K1: MFMA ea@Wa2, alpha = exp(post-bn softplus), segment sum ----------
// block = 64 edges, wave = 16 edges x 256 cols (M=16,N=256,K=64)
__global__ __launch_bounds__(256) void k_alpha(
    const float* __restrict__ ea, const int* __restrict__ src, const int* __restrict__ tgt,
    const float* __restrict__ nodeA, const short* __restrict__ WaTb,
    const float* __restrict__ att, const float* __restrict__ gamma,
    const float* __restrict__ beta,
    float* __restrict__ alphaBuf, float* __restrict__ segSum) {
    int t = threadIdx.x;
    int wave = t >> 6, lane = t & 63;
    int i = lane & 15, q = lane >> 4;
    int eb = blockIdx.x * 64 + wave * 16;

    // A fragments: lane holds ea[eb+i][kt*32 + q*8 .. +8) as bf16
    short8 afr[2];
    {
        const float* ap = ea + (size_t)(eb + i) * 64 + q * 8;
#pragma unroll
        for (int kt = 0; kt < 2; kt++) {
            float4 x0 = *(const float4*)(ap + kt * 32);
            float4 x1 = *(const float4*)(ap + kt * 32 + 4);
            short8 a;
            a[0] = f2bf(x0.x); a[1] = f2bf(x0.y); a[2] = f2bf(x0.z); a[3] = f2bf(x0.w);
            a[4] = f2bf(x1.x); a[5] = f2bf(x1.y); a[6] = f2bf(x1.z); a[7] = f2bf(x1.w);
            afr[kt] = a;
        }
    }
    // per-lane edge rows r=0..3 -> e = eb + q*4 + r
    int sI[4];
    const float *bs[4], *bt[4];
#pragma unroll
    for (int r = 0; r < 4; r++) {
        int e = eb + q * 4 + r;
        sI[r] = src[e];
        int tg = tgt[e];
        bs[r] = nodeA + (size_t)sI[r] * 640 + 384;
        bt[r] = nodeA + (size_t)tg * 640 + 384;
    }
    float part[4][4];   // [head][r]
#pragma unroll
    for (int h = 0; h < 4; h++)
#pragma unroll
        for (int r = 0; r < 4; r++) part[h][r] = 0.f;

#pragma unroll
    for (int nt = 0; nt < 16; nt++) {
        const short* wrow = WaTb + (nt * 16 + i) * 64 + q * 8;
        short8 b0 = *(const short8*)(wrow);
        short8 b1 = *(const short8*)(wrow + 32);
        fragC acc = {0.f, 0.f, 0.f, 0.f};
        acc = __builtin_amdgcn_mfma_f32_16x16x32_bf16(afr[0], b0, acc, 0, 0, 0);
        acc = __builtin_amdgcn_mfma_f32_16x16x32_bf16(afr[1], b1, acc, 0, 0, 0);
        int c = nt * 16 + i;
        int h = nt >> 2;
        float atti = att[h * 128 + (c & 63)];
        float attj = att[h * 128 + 64 + (c & 63)];
#pragma unroll
        for (int r = 0; r < 4; r++) {
            float P = acc[r];
            float oi = softplus_f(bs[r][c] + P);
            float oj = softplus_f(bt[r][c] + P);
            part[h][r] += oi * atti + oj * attj;
        }
    }
    const float inv_s = 0.99999500003749968f;  // 1/sqrt(1+1e-5)
#pragma unroll
    for (int h = 0; h < 4; h++) {
        float g = gamma[h], b = beta[h];
#pragma unroll
        for (int r = 0; r < 4; r++) {
            float p = part[h][r];
            p += __shfl_xor(p, 1);
            p += __shfl_xor(p, 2);
            p += __shfl_xor(p, 4);
            p += __shfl_xor(p, 8);
            if (i == 0) {
                float araw = softplus_f(p);
                float av = softplus_f(araw * inv_s * g + b);
                float a = __expf(av);   // no max-subtraction: av is O(1), softmax shift-invariant
                int e = eb + q * 4 + r;
                alphaBuf[e * 4 + h] = a;
                atomicAdd(&segSum[sI[r] * 4 + h], a);
            }
        }
    }
}

// ---------- K3: pw branch (2 MFMA GEMMs), ea@Wa2 again, z1, combine, scatter ----------
__global__ __launch_bounds__(256) void k_final(
    const float* __restrict__ ea, const float* __restrict__ pw,
    const float* __restrict__ rij,
    const int* __restrict__ src, const int* __restrict__ tgt,
    const float* __restrict__ nodeA, const short* __restrict__ WaTb,
    const short* __restrict__ W2gTb, const short* __restrict__ W2Tb,
    const float* __restrict__ alphaBuf, const float* __restrict__ segSum,
    float* __restrict__ out) {
    __shared__ short pwg[4][16 * 72];   // per-wave (pw*gate) bf16, row stride 72 (144B, 16B-aligned)
    int t = threadIdx.x;
    int wave = t >> 6, lane = t & 63;
    int i = lane & 15, q = lane >> 4;
    int eb = blockIdx.x * 64 + wave * 16;

    int sI[4];
    float ir[4];
    const float *bs[4], *bt[4];
    float wal[4][4];   // [r][h] = alpha/(den)*0.25
#pragma unroll
    for (int r = 0; r < 4; r++) {
        int e = eb + q * 4 + r;
        sI[r] = src[e];
        int tg = tgt[e];
        bs[r] = nodeA + (size_t)sI[r] * 640;
        bt[r] = nodeA + (size_t)tg * 640;
        float rr = rij[e];
        if (rr == 0.f) rr = 1e-8f;
        ir[r] = 1.f / rr;
#pragma unroll
        for (int h = 0; h < 4; h++) {
            wal[r][h] = alphaBuf[e * 4 + h] /
                        (segSum[sI[r] * 4 + h] + 1e-16f) * 0.25f;
        }
    }

    // ---- pw gate GEMM: G = pw @ W2gT  (16x64) ----
    short8 pfr[2];
    {
        const float* pp = pw + (size_t)(eb + i) * 64 + q * 8;
#pragma unroll
        for (int kt = 0; kt < 2; kt++) {
            float4 x0 = *(const float4*)(pp + kt * 32);
            float4 x1 = *(const float4*)(pp + kt * 32 + 4);
            short8 a;
            a[0] = f2bf(x0.x); a[1] = f2bf(x0.y); a[2] = f2bf(x0.z); a[3] = f2bf(x0.w);
            a[4] = f2bf(x1.x); a[5] = f2bf(x1.y); a[6] = f2bf(x1.z); a[7] = f2bf(x1.w);
            pfr[kt] = a;
        }
    }
#pragma unroll
    for (int nt = 0; nt < 4; nt++) {
        const short* wrow = W2gTb + (nt * 16 + i) * 64 + q * 8;
        short8 b0 = *(const short8*)(wrow);
        short8 b1 = *(const short8*)(wrow + 32);
        fragC g = {0.f, 0.f, 0.f, 0.f};
        g = __builtin_amdgcn_mfma_f32_16x16x32_bf16(pfr[0], b0, g, 0, 0, 0);
        g = __builtin_amdgcn_mfma_f32_16x16x32_bf16(pfr[1], b1, g, 0, 0, 0);
        int k = nt * 16 + i;
#pragma unroll
        for (int r = 0; r < 4; r++) {
            float pv = pw[(size_t)(eb + q * 4 + r) * 64 + k];
            pwg[wave][(q * 4 + r) * 72 + k] = f2bf(pv * sigmoid_f(g[r]));
        }
    }
    __syncthreads();

    // ---- z2 GEMM: z2 = (pw*gate) @ W2T  (16x64) ----
    short8 a2[2];
    {
        const short* prow = &pwg[wave][i * 72 + q * 8];
        a2[0] = *(const short8*)(prow);
        a2[1] = *(const short8*)(prow + 32);
    }
    fragC z2f[4];
#pragma unroll
    for (int nt = 0; nt < 4; nt++) {
        const short* wrow = W2Tb + (nt * 16 + i) * 64 + q * 8;
        short8 b0 = *(const short8*)(wrow);
        short8 b1 = *(const short8*)(wrow + 32);
        fragC z = {0.f, 0.f, 0.f, 0.f};
        z = __builtin_amdgcn_mfma_f32_16x16x32_bf16(a2[0], b0, z, 0, 0, 0);
        z = __builtin_amdgcn_mfma_f32_16x16x32_bf16(a2[1], b1, z, 0, 0, 0);
        z2f[nt] = z;
    }

    // ---- ea@Wa2 GEMM + z1 accumulation ----
    short8 afr[2];
    {
        const float* ap = ea + (size_t)(eb + i) * 64 + q * 8;
#pragma unroll
        for (int kt = 0; kt < 2; kt++) {
            float4 x0 = *(const float4*)(ap + kt * 32);
            float4 x1 = *(const float4*)(ap + kt * 32 + 4);
            short8 a;
            a[0] = f2bf(x0.x); a[1] = f2bf(x0.y); a[2] = f2bf(x0.z); a[3] = f2bf(x0.w);
            a[4] = f2bf(x1.x); a[5] = f2bf(x1.y); a[6] = f2bf(x1.z); a[7] = f2bf(x1.w);
            afr[kt] = a;
        }
    }
    float z1[4][4];   // [j = d>>4][r]
#pragma unroll
    for (int j = 0; j < 4; j++)
#pragma unroll
        for (int r = 0; r < 4; r++) z1[j][r] = 0.f;
#pragma unroll
    for (int nt = 0; nt < 16; nt++) {
        const short* wrow = WaTb + (nt * 16 + i) * 64 + q * 8;
        short8 b0 = *(const short8*)(wrow);
        short8 b1 = *(const short8*)(wrow + 32);
        fragC acc = {0.f, 0.f, 0.f, 0.f};
        acc = __builtin_amdgcn_mfma_f32_16x16x32_bf16(afr[0], b0, acc, 0, 0, 0);
        acc = __builtin_amdgcn_mfma_f32_16x16x32_bf16(afr[1], b1, acc, 0, 0, 0);
        int c = nt * 16 + i;
        int h = nt >> 2, j = nt & 3;
#pragma unroll
        for (int r = 0; r < 4; r++) {
            float oj = softplus_f(bt[r][384 + c] + acc[r]);
            z1[j][r] += oj * wal[r][h];
        }
    }

    // ---- gate/mlp branch + combine + scatter ----
#pragma unroll
    for (int j = 0; j < 4; j++) {
        int d = j * 16 + i;
#pragma unroll
        for (int r = 0; r < 4; r++) {
            const float* As = bs[r];
            const float* At = bt[r];
            float gl = As[d] + At[64 + d] + (As[128 + d] - At[128 + d]) * ir[r];
            float ml = As[192 + d] + At[256 + d] + (As[320 + d] - At[320 + d]) * ir[r];
            float eg = sigmoid_f(gl);
            float em = ml > 0.f ? ml : (__expf(ml) - 1.f);
            float z = eg * em * (z1[j][r] + z2f[j][r]);
            atomicAdd(&out[(size_t)sI[r] * 64 + d], z);
        }
    }
}

extern "C" void kernel_launch(void* const* d_in, const int* in_sizes, int n_in,
                              void* d_out, int out_size, void* d_ws, size_t ws_size,
                              hipStream_t stream) {
    const float* input = (const float*)d_in[0];
    const float* rij   = (const float*)d_in[1];
    const float* pw    = (const float*)d_in[2];
    const float* ea    = (const float*)d_in[3];
    const float* Wg    = (const float*)d_in[4];
    const float* Wm    = (const float*)d_in[5];
    const float* W2    = (const float*)d_in[6];
    const float* W2g   = (const float*)d_in[7];
    const float* Wa    = (const float*)d_in[8];
    const float* att   = (const float*)d_in[9];
    const float* gamma = (const float*)d_in[10];
    const float* beta  = (const float*)d_in[11];
    const int* srcIdx  = (const int*)d_in[12];
    const int* tgtIdx  = (const int*)d_in[13];
    float* out = (float*)d_out;

    // workspace layout (bytes)
    char* wsb = (char*)d_ws;
    float* nodeA    = (float*)(wsb);                      // 40000*640*4 = 102,400,000
    float* alphaBuf = (float*)(wsb + 102400000);          // 640000*4*4  = 10,240,000
    float* segSum   = (float*)(wsb + 112640000);          // 640,000
    short* WaTb     = (short*)(wsb + 113280000);          // 32,768
    short* W2gTb    = (short*)(wsb + 113312768);          // 8,192
    short* W2Tb     = (short*)(wsb + 113320960);          // 8,192

    hipMemsetAsync(wsb + 112640000, 0, 640000, stream);   // segSum = 0
    // out = input  (scatter-add target)
    hipMemcpyAsync(d_out, (const void*)input, (size_t)N_NODES * 64 * sizeof(float),
                   hipMemcpyDeviceToDevice, stream);

    k_weights<<<32, 256, 0, stream>>>(Wa, W2g, W2, WaTb, W2gTb, W2Tb);
    k_node_pre<<<N_NODES / NT0, 256, 0, stream>>>(input, Wg, Wm, Wa, nodeA);
    k_alpha<<<N_EDGES / 64, 256, 0, stream>>>(ea, srcIdx, tgtIdx, nodeA, WaTb,
                                              att, gamma, beta, alphaBuf, segSum);
    k_final<<<N_EDGES / 64, 256, 0, stream>>>(ea, pw, rij, srcIdx, tgtIdx, nodeA,
                                              WaTb, W2gTb, W2Tb, alphaBuf, segSum, out);
}

// Round 3
// 1080.764 us; speedup vs baseline: 4.2449x; 2.8660x over previous
//
#include <hip/hip_runtime.h>
#include <math.h>

#define N_NODES 40000
#define N_EDGES 640000
#define NT0 16

typedef short short8 __attribute__((ext_vector_type(8)));
typedef unsigned short ushort8v __attribute__((ext_vector_type(8)));
typedef unsigned short ushort4v __attribute__((ext_vector_type(4)));
typedef float fragC __attribute__((ext_vector_type(4)));

__device__ __forceinline__ float softplus_f(float x) {
    return x > 15.f ? x : __logf(1.f + __expf(x));
}
__device__ __forceinline__ float sigmoid_f(float x) {
    return 1.f / (1.f + __expf(-x));
}
__device__ __forceinline__ short f2bf(float f) {
    unsigned u = __float_as_uint(f);
    u += 0x7FFF + ((u >> 16) & 1);   // round-to-nearest-even
    return (short)(u >> 16);
}
__device__ __forceinline__ float bf2f(unsigned short u) {
    return __uint_as_float(((unsigned)u) << 16);
}

// ---------- bf16 weight prep ----------
__global__ void k_weights(const float* __restrict__ Wa, const float* __restrict__ W2g,
                          const float* __restrict__ W2, short* __restrict__ WaTb,
                          short* __restrict__ W2gTb, short* __restrict__ W2Tb) {
    int idx = blockIdx.x * blockDim.x + threadIdx.x;
    int stride = gridDim.x * blockDim.x;
    for (int i = idx; i < 256 * 64; i += stride) {
        int c = i >> 6, k = i & 63;
        WaTb[i] = f2bf(Wa[(64 + k) * 256 + c]);
    }
    for (int i = idx; i < 64 * 64; i += stride) {
        int c = i >> 6, k = i & 63;
        W2gTb[i] = f2bf(W2g[k * 64 + c]);
        W2Tb[i]  = f2bf(W2[k * 64 + c]);
    }
}

// ---------- K0: node precompute into transposed/packed tables ----------
// nodeAxaT (bf16): [n][ (co&15)*16 + (co>>4) ]  co = col of input@Wa_nodehalf (0..255)
// nodeGT   (bf16): [n][ Ag1 | Ag2 | Am1 | Am2 ] each 64, idx (d&15)*4 + (d>>4)
// nodeDT   (fp32): [n][ Ag3 | Am3 ] each 64, idx (d&15)*4 + (d>>4)
__global__ __launch_bounds__(256) void k_node_pre(const float* __restrict__ X,
                                                  const float* __restrict__ Wg,
                                                  const float* __restrict__ Wm,
                                                  const float* __restrict__ Wa,
                                                  short* __restrict__ nodeAxaT,
                                                  short* __restrict__ nodeGT,
                                                  float* __restrict__ nodeDT) {
    __shared__ float xs[NT0 * 64];
    int t = threadIdx.x;
    int n0 = blockIdx.x * NT0;
    ((float4*)xs)[t] = ((const float4*)(X + (size_t)n0 * 64))[t];
    __syncthreads();
    for (int c = t; c < 640; c += 256) {
        const float* wptr;
        int ld;
        if (c < 192)      { wptr = Wg + (c >> 6) * 64 * 64 + (c & 63); ld = 64; }
        else if (c < 384) { wptr = Wm + ((c - 192) >> 6) * 64 * 64 + (c & 63); ld = 64; }
        else              { wptr = Wa + (c - 384); ld = 256; }
        float acc[NT0];
#pragma unroll
        for (int n = 0; n < NT0; n++) acc[n] = 0.f;
        for (int kc = 0; kc < 16; kc++) {
            float w0 = wptr[(4 * kc + 0) * ld];
            float w1 = wptr[(4 * kc + 1) * ld];
            float w2 = wptr[(4 * kc + 2) * ld];
            float w3 = wptr[(4 * kc + 3) * ld];
#pragma unroll
            for (int n = 0; n < NT0; n++) {
                float4 x = ((float4*)xs)[n * 16 + kc];
                acc[n] += x.x * w0 + x.y * w1 + x.z * w2 + x.w * w3;
            }
        }
#pragma unroll
        for (int n = 0; n < NT0; n++) {
            float v = acc[n];
            size_t nn = (size_t)(n0 + n);
            if (c < 64) {
                nodeGT[nn * 256 + (c & 15) * 4 + (c >> 4)] = f2bf(v);              // Ag1
            } else if (c < 128) {
                int d = c - 64;  nodeGT[nn * 256 + 64 + (d & 15) * 4 + (d >> 4)] = f2bf(v);   // Ag2
            } else if (c < 192) {
                int d = c - 128; nodeDT[nn * 128 + (d & 15) * 4 + (d >> 4)] = v;              // Ag3
            } else if (c < 256) {
                int d = c - 192; nodeGT[nn * 256 + 128 + (d & 15) * 4 + (d >> 4)] = f2bf(v);  // Am1
            } else if (c < 320) {
                int d = c - 256; nodeGT[nn * 256 + 192 + (d & 15) * 4 + (d >> 4)] = f2bf(v);  // Am2
            } else if (c < 384) {
                int d = c - 320; nodeDT[nn * 128 + 64 + (d & 15) * 4 + (d >> 4)] = v;         // Am3
            } else {
                int co = c - 384; nodeAxaT[nn * 256 + (co & 15) * 16 + (co >> 4)] = f2bf(v);  // Axa
            }
        }
    }
}

// ---------- K1: MFMA ea@Wa2, alpha, segment sum ----------
__global__ __launch_bounds__(256) void k_alpha(
    const float* __restrict__ ea, const int* __restrict__ src, const int* __restrict__ tgt,
    const unsigned short* __restrict__ nodeAxaT, const short* __restrict__ WaTb,
    const float* __restrict__ att, const float* __restrict__ gamma,
    const float* __restrict__ beta,
    float* __restrict__ alphaBuf, float* __restrict__ segSum) {
    __shared__ short ldsW[256 * 72];   // swizzled row stride 72 shorts (144B)
    __shared__ float attS[512];
    int t = threadIdx.x;
    {
        const float4* s4 = (const float4*)(WaTb + t * 64);
        float4* d4 = (float4*)(ldsW + t * 72);
#pragma unroll
        for (int k = 0; k < 8; k++) d4[k] = s4[k];
        attS[t] = att[(t >> 6) * 128 + (t & 63)];
        attS[256 + t] = att[(t >> 6) * 128 + 64 + (t & 63)];
    }
    __syncthreads();
    int wave = t >> 6, lane = t & 63;
    int i = lane & 15, q = lane >> 4;
    int eb = blockIdx.x * 64 + wave * 16;

    // A fragments from ea (fp32 -> bf16)
    short8 afr[2];
    {
        const float* ap = ea + (size_t)(eb + i) * 64 + q * 8;
#pragma unroll
        for (int kt = 0; kt < 2; kt++) {
            float4 x0 = *(const float4*)(ap + kt * 32);
            float4 x1 = *(const float4*)(ap + kt * 32 + 4);
            short8 a;
            a[0] = f2bf(x0.x); a[1] = f2bf(x0.y); a[2] = f2bf(x0.z); a[3] = f2bf(x0.w);
            a[4] = f2bf(x1.x); a[5] = f2bf(x1.y); a[6] = f2bf(x1.z); a[7] = f2bf(x1.w);
            afr[kt] = a;
        }
    }
    // per-r node gathers: one b128 pair per side
    int sI[4];
    ushort8v gs[4][2], gt[4][2];
#pragma unroll
    for (int r = 0; r < 4; r++) {
        int e = eb + q * 4 + r;
        sI[r] = src[e];
        int tg = tgt[e];
        const unsigned short* ps = nodeAxaT + (size_t)sI[r] * 256 + i * 16;
        const unsigned short* pt = nodeAxaT + (size_t)tg * 256 + i * 16;
        gs[r][0] = *(const ushort8v*)(ps);
        gs[r][1] = *(const ushort8v*)(ps + 8);
        gt[r][0] = *(const ushort8v*)(pt);
        gt[r][1] = *(const ushort8v*)(pt + 8);
    }
    float part[4][4];
#pragma unroll
    for (int h = 0; h < 4; h++)
#pragma unroll
        for (int r = 0; r < 4; r++) part[h][r] = 0.f;

#pragma unroll
    for (int nt = 0; nt < 16; nt++) {
        const short* wrow = ldsW + (nt * 16 + i) * 72 + q * 8;
        short8 b0 = *(const short8*)(wrow);
        short8 b1 = *(const short8*)(wrow + 32);
        fragC acc = {0.f, 0.f, 0.f, 0.f};
        acc = __builtin_amdgcn_mfma_f32_16x16x32_bf16(afr[0], b0, acc, 0, 0, 0);
        acc = __builtin_amdgcn_mfma_f32_16x16x32_bf16(afr[1], b1, acc, 0, 0, 0);
        float atti = attS[nt * 16 + i];
        float attj = attS[256 + nt * 16 + i];
        int h = nt >> 2;
#pragma unroll
        for (int r = 0; r < 4; r++) {
            float P = acc[r];
            float oi = softplus_f(bf2f(gs[r][nt >> 3][nt & 7]) + P);
            float oj = softplus_f(bf2f(gt[r][nt >> 3][nt & 7]) + P);
            part[h][r] += oi * atti + oj * attj;
        }
    }
    const float inv_s = 0.99999500003749968f;
#pragma unroll
    for (int h = 0; h < 4; h++) {
        float g = gamma[h], b = beta[h];
#pragma unroll
        for (int r = 0; r < 4; r++) {
            float p = part[h][r];
            p += __shfl_xor(p, 1);
            p += __shfl_xor(p, 2);
            p += __shfl_xor(p, 4);
            p += __shfl_xor(p, 8);
            if (i == 0) {
                float araw = softplus_f(p);
                float av = softplus_f(araw * inv_s * g + b);
                float a = __expf(av);
                int e = eb + q * 4 + r;
                alphaBuf[e * 4 + h] = a;
                atomicAdd(&segSum[sI[r] * 4 + h], a);
            }
        }
    }
}

// ---------- K3: pw branch, ea@Wa2 + z1, combine, scatter ----------
__global__ __launch_bounds__(256) void k_final(
    const float* __restrict__ ea, const float* __restrict__ pw,
    const float* __restrict__ rij,
    const int* __restrict__ src, const int* __restrict__ tgt,
    const unsigned short* __restrict__ nodeAxaT, const unsigned short* __restrict__ nodeGT,
    const float* __restrict__ nodeDT,
    const short* __restrict__ WaTb, const short* __restrict__ W2gTb,
    const short* __restrict__ W2Tb,
    const float* __restrict__ alphaBuf, const float* __restrict__ segSum,
    float* __restrict__ out) {
    __shared__ short ldsW[256 * 72];
    __shared__ short pwg[4][16 * 72];
    int t = threadIdx.x;
    {
        const float4* s4 = (const float4*)(WaTb + t * 64);
        float4* d4 = (float4*)(ldsW + t * 72);
#pragma unroll
        for (int k = 0; k < 8; k++) d4[k] = s4[k];
    }
    int wave = t >> 6, lane = t & 63;
    int i = lane & 15, q = lane >> 4;
    int eb = blockIdx.x * 64 + wave * 16;

    int sI[4], tgI[4];
    float ir[4];
    float wal[4][4];
    ushort8v ga[4][2];   // target Axa rows
#pragma unroll
    for (int r = 0; r < 4; r++) {
        int e = eb + q * 4 + r;
        sI[r] = src[e];
        tgI[r] = tgt[e];
        float rr = rij[e];
        if (rr == 0.f) rr = 1e-8f;
        ir[r] = 1.f / rr;
        float4 av = *(const float4*)(alphaBuf + (size_t)e * 4);
        float4 sv = *(const float4*)(segSum + (size_t)sI[r] * 4);
        wal[r][0] = av.x / (sv.x + 1e-16f) * 0.25f;
        wal[r][1] = av.y / (sv.y + 1e-16f) * 0.25f;
        wal[r][2] = av.z / (sv.z + 1e-16f) * 0.25f;
        wal[r][3] = av.w / (sv.w + 1e-16f) * 0.25f;
        const unsigned short* pt = nodeAxaT + (size_t)tgI[r] * 256 + i * 16;
        ga[r][0] = *(const ushort8v*)(pt);
        ga[r][1] = *(const ushort8v*)(pt + 8);
    }

    // ---- pw gate GEMM ----
    short8 pfr[2];
    {
        const float* pp = pw + (size_t)(eb + i) * 64 + q * 8;
#pragma unroll
        for (int kt = 0; kt < 2; kt++) {
            float4 x0 = *(const float4*)(pp + kt * 32);
            float4 x1 = *(const float4*)(pp + kt * 32 + 4);
            short8 a;
            a[0] = f2bf(x0.x); a[1] = f2bf(x0.y); a[2] = f2bf(x0.z); a[3] = f2bf(x0.w);
            a[4] = f2bf(x1.x); a[5] = f2bf(x1.y); a[6] = f2bf(x1.z); a[7] = f2bf(x1.w);
            pfr[kt] = a;
        }
    }
#pragma unroll
    for (int nt = 0; nt < 4; nt++) {
        const short* wrow = W2gTb + (nt * 16 + i) * 64 + q * 8;
        short8 b0 = *(const short8*)(wrow);
        short8 b1 = *(const short8*)(wrow + 32);
        fragC g = {0.f, 0.f, 0.f, 0.f};
        g = __builtin_amdgcn_mfma_f32_16x16x32_bf16(pfr[0], b0, g, 0, 0, 0);
        g = __builtin_amdgcn_mfma_f32_16x16x32_bf16(pfr[1], b1, g, 0, 0, 0);
        int k = nt * 16 + i;
#pragma unroll
        for (int r = 0; r < 4; r++) {
            float pv = pw[(size_t)(eb + q * 4 + r) * 64 + k];
            pwg[wave][(q * 4 + r) * 72 + k] = f2bf(pv * sigmoid_f(g[r]));
        }
    }
    __syncthreads();   // covers ldsW staging + pwg writes

    // ---- z2 GEMM ----
    short8 a2[2];
    {
        const short* prow = &pwg[wave][i * 72 + q * 8];
        a2[0] = *(const short8*)(prow);
        a2[1] = *(const short8*)(prow + 32);
    }
    fragC z2f[4];
#pragma unroll
    for (int nt = 0; nt < 4; nt++) {
        const short* wrow = W2Tb + (nt * 16 + i) * 64 + q * 8;
        short8 b0 = *(const short8*)(wrow);
        short8 b1 = *(const short8*)(wrow + 32);
        fragC z = {0.f, 0.f, 0.f, 0.f};
        z = __builtin_amdgcn_mfma_f32_16x16x32_bf16(a2[0], b0, z, 0, 0, 0);
        z = __builtin_amdgcn_mfma_f32_16x16x32_bf16(a2[1], b1, z, 0, 0, 0);
        z2f[nt] = z;
    }

    // ---- ea@Wa2 + z1 ----
    short8 afr[2];
    {
        const float* ap = ea + (size_t)(eb + i) * 64 + q * 8;
#pragma unroll
        for (int kt = 0; kt < 2; kt++) {
            float4 x0 = *(const float4*)(ap + kt * 32);
            float4 x1 = *(const float4*)(ap + kt * 32 + 4);
            short8 a;
            a[0] = f2bf(x0.x); a[1] = f2bf(x0.y); a[2] = f2bf(x0.z); a[3] = f2bf(x0.w);
            a[4] = f2bf(x1.x); a[5] = f2bf(x1.y); a[6] = f2bf(x1.z); a[7] = f2bf(x1.w);
            afr[kt] = a;
        }
    }
    float z1[4][4];
#pragma unroll
    for (int j = 0; j < 4; j++)
#pragma unroll
        for (int r = 0; r < 4; r++) z1[j][r] = 0.f;
#pragma unroll
    for (int nt = 0; nt < 16; nt++) {
        const short* wrow = ldsW + (nt * 16 + i) * 72 + q * 8;
        short8 b0 = *(const short8*)(wrow);
        short8 b1 = *(const short8*)(wrow + 32);
        fragC acc = {0.f, 0.f, 0.f, 0.f};
        acc = __builtin_amdgcn_mfma_f32_16x16x32_bf16(afr[0], b0, acc, 0, 0, 0);
        acc = __builtin_amdgcn_mfma_f32_16x16x32_bf16(afr[1], b1, acc, 0, 0, 0);
        int h = nt >> 2, j = nt & 3;
#pragma unroll
        for (int r = 0; r < 4; r++) {
            float oj = softplus_f(bf2f(ga[r][nt >> 3][nt & 7]) + acc[r]);
            z1[j][r] += oj * wal[r][h];
        }
    }

    // ---- epilogue per edge ----
#pragma unroll
    for (int r = 0; r < 4; r++) {
        const unsigned short* Gs = nodeGT + (size_t)sI[r] * 256;
        const unsigned short* Gt = nodeGT + (size_t)tgI[r] * 256;
        const float* Ds = nodeDT + (size_t)sI[r] * 128;
        const float* Dt = nodeDT + (size_t)tgI[r] * 128;
        ushort4v ag1 = *(const ushort4v*)(Gs + i * 4);
        ushort4v am1 = *(const ushort4v*)(Gs + 128 + i * 4);
        ushort4v ag2 = *(const ushort4v*)(Gt + 64 + i * 4);
        ushort4v am2 = *(const ushort4v*)(Gt + 192 + i * 4);
        float4 ag3s = *(const float4*)(Ds + i * 4);
        float4 am3s = *(const float4*)(Ds + 64 + i * 4);
        float4 ag3t = *(const float4*)(Dt + i * 4);
        float4 am3t = *(const float4*)(Dt + 64 + i * 4);
        float g3s[4] = {ag3s.x, ag3s.y, ag3s.z, ag3s.w};
        float m3s[4] = {am3s.x, am3s.y, am3s.z, am3s.w};
        float g3t[4] = {ag3t.x, ag3t.y, ag3t.z, ag3t.w};
        float m3t[4] = {am3t.x, am3t.y, am3t.z, am3t.w};
#pragma unroll
        for (int j = 0; j < 4; j++) {
            int d = j * 16 + i;
            float gl = bf2f(ag1[j]) + bf2f(ag2[j]) + (g3s[j] - g3t[j]) * ir[r];
            float ml = bf2f(am1[j]) + bf2f(am2[j]) + (m3s[j] - m3t[j]) * ir[r];
            float eg = sigmoid_f(gl);
            float em = ml > 0.f ? ml : (__expf(ml) - 1.f);
            float z = eg * em * (z1[j][r] + z2f[j][r]);
            atomicAdd(&out[(size_t)sI[r] * 64 + d], z);
        }
    }
}

extern "C" void kernel_launch(void* const* d_in, const int* in_sizes, int n_in,
                              void* d_out, int out_size, void* d_ws, size_t ws_size,
                              hipStream_t stream) {
    const float* input = (const float*)d_in[0];
    const float* rij   = (const float*)d_in[1];
    const float* pw    = (const float*)d_in[2];
    const float* ea    = (const float*)d_in[3];
    const float* Wg    = (const float*)d_in[4];
    const float* Wm    = (const float*)d_in[5];
    const float* W2    = (const float*)d_in[6];
    const float* W2g   = (const float*)d_in[7];
    const float* Wa    = (const float*)d_in[8];
    const float* att   = (const float*)d_in[9];
    const float* gamma = (const float*)d_in[10];
    const float* beta  = (const float*)d_in[11];
    const int* srcIdx  = (const int*)d_in[12];
    const int* tgtIdx  = (const int*)d_in[13];
    float* out = (float*)d_out;

    char* wsb = (char*)d_ws;
    short* nodeAxaT = (short*)(wsb);                      // 20,480,000
    short* nodeGT   = (short*)(wsb + 20480000);           // 20,480,000
    float* nodeDT   = (float*)(wsb + 40960000);           // 20,480,000
    float* alphaBuf = (float*)(wsb + 61440000);           // 10,240,000
    float* segSum   = (float*)(wsb + 71680000);           // 640,000
    short* WaTb     = (short*)(wsb + 72320000);           // 32,768
    short* W2gTb    = (short*)(wsb + 72352768);           // 8,192
    short* W2Tb     = (short*)(wsb + 72360960);           // 8,192

    hipMemsetAsync(wsb + 71680000, 0, 640000, stream);    // segSum = 0
    hipMemcpyAsync(d_out, (const void*)input, (size_t)N_NODES * 64 * sizeof(float),
                   hipMemcpyDeviceToDevice, stream);

    k_weights<<<32, 256, 0, stream>>>(Wa, W2g, W2, WaTb, W2gTb, W2Tb);
    k_node_pre<<<N_NODES / NT0, 256, 0, stream>>>(input, Wg, Wm, Wa,
                                                  nodeAxaT, nodeGT, nodeDT);
    k_alpha<<<N_EDGES / 64, 256, 0, stream>>>(ea, srcIdx, tgtIdx,
                                              (const unsigned short*)nodeAxaT, WaTb,
                                              att, gamma, beta, alphaBuf, segSum);
    k_final<<<N_EDGES / 64, 256, 0, stream>>>(ea, pw, rij, srcIdx, tgtIdx,
                                              (const unsigned short*)nodeAxaT,
                                              (const unsigned short*)nodeGT, nodeDT,
                                              WaTb, W2gTb, W2Tb, alphaBuf, segSum, out);
}